// Round 9
// baseline (276.687 us; speedup 1.0000x reference)
//
#include <hip/hip_runtime.h>

// ---------------------------------------------------------------------------
// GCN encoder: out = GCNConv2( relu(GCNConv1(x)) )
// R8: channel-blocked h (4x/2x planes of [N][32] fp16) + one gather dispatch
// per plane so the random-gather footprint (3.2 MB) fits per-XCD L2.
// Parallel colscan replaces the single-block bscan. GEMM (R7 async LDS,
// fp16 MFMA) unchanged except blocked-plane epilogue.
// ---------------------------------------------------------------------------

typedef __attribute__((ext_vector_type(4))) float floatx4;
typedef _Float16 __attribute__((ext_vector_type(8))) half8v;

#define BUCK_SH 6
#define BUCK    64           // dsts per bucket
#define NBLK    256          // blocks for hist2/scatter2

#define AS1(p) ((const __attribute__((address_space(1))) void*)(p))
#define AS3(p) ((__attribute__((address_space(3))) void*)(p))

// edge_index may arrive as int64 (reference dtype) or int32 (harness contract).
__global__ void detect64_kernel(const int* __restrict__ ei, int* __restrict__ flag) {
    __shared__ int nz;
    if (threadIdx.x == 0) nz = 0;
    __syncthreads();
    if (ei[2 * threadIdx.x + 1] != 0) atomicOr(&nz, 1);
    __syncthreads();
    if (threadIdx.x == 0) *flag = (nz == 0) ? 1 : 0;
}

__device__ __forceinline__ int edge_id(const int* __restrict__ ei, int is64, long long pos) {
    return is64 ? ei[2 * pos] : ei[(int)pos];
}

// ---- per-block bucket histogram -> hist2[blk][NB] (no global atomics) ------
__global__ void hist2_kernel(const int* __restrict__ ei, const int* __restrict__ flag,
                             int* __restrict__ hist2, int E, int NB, int chunk) {
    __shared__ int h[1024];
    const int t = threadIdx.x;
    for (int i = t; i < NB; i += blockDim.x) h[i] = 0;
    __syncthreads();
    const int is64 = *flag;
    const int lo = blockIdx.x * chunk;
    const int hi = min(E, lo + chunk);
    for (int e = lo + t; e < hi; e += blockDim.x) {
        int d = edge_id(ei, is64, (long long)E + e);
        atomicAdd(&h[d >> BUCK_SH], 1);
    }
    __syncthreads();
    for (int i = t; i < NB; i += blockDim.x) hist2[(long long)blockIdx.x * NB + i] = h[i];
}

// ---- per-bucket column scan: start2t[bucket][blk] + colsum[bucket] ---------
__global__ void colscan_kernel(const int* __restrict__ hist2, int* __restrict__ start2t,
                               int* __restrict__ colsum, int NB) {
    int t = blockIdx.x * blockDim.x + threadIdx.x;    // bucket id
    if (t >= NB) return;
    int run = 0;
    for (int b = 0; b < NBLK; ++b) {
        int v = hist2[(long long)b * NB + t];         // coalesced across wave
        start2t[(long long)t * NBLK + b] = run;       // contiguous per thread
        run += v;
    }
    colsum[t] = run;
}

// ---- tiny single-block exclusive scan of colsum -> bbase[NB+1] -------------
__global__ void basescan_kernel(const int* __restrict__ colsum, int* __restrict__ bbase,
                                int NB, int E) {
    __shared__ int sm[1024];
    const int t = threadIdx.x;
    int v = (t < NB) ? colsum[t] : 0;
    sm[t] = v;
    __syncthreads();
    for (int s = 1; s < 1024; s <<= 1) {
        int u = (t >= s) ? sm[t - s] : 0;
        __syncthreads();
        sm[t] += u;
        __syncthreads();
    }
    if (t < NB) bbase[t] = sm[t] - v;
    if (t == 0) bbase[NB] = E;
}

// ---- scatter: LDS cursors only, packed record src | (dlocal<<26) -----------
__global__ void scatter2_kernel(const int* __restrict__ ei, const int* __restrict__ flag,
                                const int* __restrict__ bbase, const int* __restrict__ start2t,
                                unsigned* __restrict__ ebuf, int E, int NB, int chunk) {
    __shared__ int hcur[1024];
    const int t = threadIdx.x;
    for (int i = t; i < NB; i += blockDim.x)
        hcur[i] = bbase[i] + start2t[(long long)i * NBLK + blockIdx.x];
    __syncthreads();
    const int is64 = *flag;
    const int lo = blockIdx.x * chunk;
    const int hi = min(E, lo + chunk);
    for (int e = lo + t; e < hi; e += blockDim.x) {
        int s = edge_id(ei, is64, e);
        int d = edge_id(ei, is64, (long long)E + e);
        int pos = atomicAdd(&hcur[d >> BUCK_SH], 1);
        ebuf[pos] = (unsigned)s | ((unsigned)(d & (BUCK - 1)) << 26);
    }
}

// ---- per-bucket exact CSR build: offs, dinv, csr(src only) -----------------
__global__ void csrbuild_kernel(const unsigned* __restrict__ ebuf, const int* __restrict__ bbase,
                                int* __restrict__ offs, float* __restrict__ dinv,
                                int* __restrict__ csr, int N, int NB, int E) {
    __shared__ int cnt[BUCK], exc[BUCK], cur[BUCK];
    const int b = blockIdx.x;
    const int t = threadIdx.x;
    if (t < BUCK) { cnt[t] = 0; cur[t] = 0; }
    __syncthreads();
    const int lo = bbase[b], hi = bbase[b + 1];
    for (int i = lo + t; i < hi; i += blockDim.x)
        atomicAdd(&cnt[ebuf[i] >> 26], 1);
    __syncthreads();
    if (t == 0) {
        int run = 0;
        for (int l = 0; l < BUCK; ++l) { exc[l] = run; run += cnt[l]; }
    }
    __syncthreads();
    if (t < BUCK) {
        int n = b * BUCK + t;
        if (n < N) {
            offs[n] = lo + exc[t];
            dinv[n] = rsqrtf(1.0f + (float)cnt[t]);
        }
    }
    if (b == NB - 1 && t == 0) offs[N] = E;
    for (int i = lo + t; i < hi; i += blockDim.x) {
        unsigned e = ebuf[i];
        int l = e >> 26;
        int p = lo + exc[l] + atomicAdd(&cur[l], 1);
        csr[p] = (int)(e & 0x03FFFFFFu);
    }
}

// ---------------------------------------------------------------------------
// Weight pre-transform: W[K][Nc] fp32 -> Wt [Nc][K] fp16
// ---------------------------------------------------------------------------
__device__ __forceinline__ void convW_one(const float* W, _Float16* Wt, int K, int Nc, int idx) {
    if (idx >= K * Nc) return;
    int k = idx / Nc, n = idx % Nc;
    Wt[(long long)n * K + k] = (_Float16)W[idx];
}

__global__ void convW_kernel(const float* __restrict__ W1, _Float16* __restrict__ T1,
                             int K1, int N1, int nb1,
                             const float* __restrict__ W2, _Float16* __restrict__ T2,
                             int K2, int N2) {
    if ((int)blockIdx.x < nb1) {
        convW_one(W1, T1, K1, N1, blockIdx.x * blockDim.x + threadIdx.x);
    } else {
        convW_one(W2, T2, K2, N2, (blockIdx.x - nb1) * blockDim.x + threadIdx.x);
    }
}

// ---------------------------------------------------------------------------
// fp16 MFMA GEMM: Cq (channel-blocked planes [col>>5][M][32] fp16)
//   = A[M,K](fp32) @ B[K,NCOL], B pre-transposed fp16 [NCOL][K].
// BM=128, BK=64, async global_load_lds staging, XOR-swizzled LDS units.
// ---------------------------------------------------------------------------
template <int NCOL, int K>
__launch_bounds__(256)
__global__ void gemm_f16_kernel(const float* __restrict__ A,
                                const _Float16* __restrict__ Bt,
                                _Float16* __restrict__ C, int M) {
    constexpr int NCB = NCOL / 16;
    constexpr int BM = 128, BK = 64;
    constexpr int NC = K / BK;                 // 4 (GEMM1) / 2 (GEMM2)
    constexpr int UNITS = BM * BK / 4;         // 16B units per chunk = 2048
    __shared__ float As[2][BM * BK];           // 2 x 32 KB

    const int tid  = threadIdx.x;
    const int wave = tid >> 6;
    const int lane = tid & 63;
    const int n15  = lane & 15;
    const int q    = lane >> 4;
    const int row0 = blockIdx.x * BM;

    floatx4 acc[2][NCB];
#pragma unroll
    for (int rt = 0; rt < 2; ++rt)
#pragma unroll
        for (int c = 0; c < NCB; ++c) acc[rt][c] = (floatx4){0.f, 0.f, 0.f, 0.f};

    auto stage = [&](int buf, int kc) {
#pragma unroll
        for (int j = 0; j < UNITS / 256; ++j) {
            int g = j * 256 + tid;
            int r = g >> 4;
            int u = (g & 15) ^ (r & 15);
            int gr = row0 + r;
            if (gr >= M) gr = M - 1;
            const float* gp = &A[(long long)gr * K + kc + u * 4];
            float* lp = &As[buf][g * 4];
            __builtin_amdgcn_global_load_lds(AS1(gp), AS3(lp), 16, 0, 0);
        }
    };

    stage(0, 0);
    __syncthreads();

#pragma unroll
    for (int c = 0; c < NC; ++c) {
        if (c + 1 < NC) stage((c + 1) & 1, (c + 1) * BK);   // async prefetch
        const int buf = c & 1;
#pragma unroll
        for (int ks = 0; ks < 2; ++ks) {                    // two K=32 sub-steps
            half8v af[2];
#pragma unroll
            for (int rt = 0; rt < 2; ++rt) {
                const int R = wave * 32 + rt * 16 + n15;
                const int u0 = ks * 8 + q * 2;
                const int p0 = (u0)     ^ (R & 15);
                const int p1 = (u0 + 1) ^ (R & 15);
                float4 f0 = *(const float4*)&As[buf][R * BK + p0 * 4];
                float4 f1 = *(const float4*)&As[buf][R * BK + p1 * 4];
                af[rt][0] = (_Float16)f0.x; af[rt][1] = (_Float16)f0.y;
                af[rt][2] = (_Float16)f0.z; af[rt][3] = (_Float16)f0.w;
                af[rt][4] = (_Float16)f1.x; af[rt][5] = (_Float16)f1.y;
                af[rt][6] = (_Float16)f1.z; af[rt][7] = (_Float16)f1.w;
            }
#pragma unroll
            for (int cb = 0; cb < NCB; ++cb) {
                const _Float16* bp = &Bt[(long long)(cb * 16 + n15) * K + c * BK + ks * 32 + q * 8];
                half8v bf = *(const half8v*)bp;
                acc[0][cb] = __builtin_amdgcn_mfma_f32_16x16x32_f16(af[0], bf, acc[0][cb], 0, 0, 0);
                acc[1][cb] = __builtin_amdgcn_mfma_f32_16x16x32_f16(af[1], bf, acc[1][cb], 0, 0, 0);
            }
        }
        if (c + 1 < NC) __syncthreads();
    }

    // C/D layout: col = cb*16 + n15, row-in-tile = q*4 + reg.
    // Write channel-blocked plane: plane = col>>5, within = col&31.
#pragma unroll
    for (int rt = 0; rt < 2; ++rt) {
#pragma unroll
        for (int cb = 0; cb < NCB; ++cb) {
            int col = cb * 16 + n15;
            long long pbase = (long long)(col >> 5) * M * 32 + (col & 31);
#pragma unroll
            for (int r = 0; r < 4; ++r) {
                int gr = row0 + wave * 32 + rt * 16 + q * 4 + r;
                if (gr < M) C[pbase + (long long)gr * 32] = (_Float16)acc[rt][cb][r];
            }
        }
    }
}

// ---------------------------------------------------------------------------
// Per-plane gather: hq = one [N][32] fp16 plane (3.2 MB, fits per-XCD L2).
// outp[n*ostride + c] = (hq[n]*dinv[n]^2 + sum_e hq[src]*dinv[src]*dinv[n])
//                        + bias[c] (, relu).  4 lanes/node, 8ch/lane.
// ---------------------------------------------------------------------------
template <int RELU>
__launch_bounds__(256)
__global__ void gatherq_kernel(const _Float16* __restrict__ hq, const int* __restrict__ csr,
                               const int* __restrict__ offs, const float* __restrict__ dinv,
                               const float* __restrict__ bias, float* __restrict__ outp,
                               int ostride, int N) {
    const int n = blockIdx.x * 64 + (threadIdx.x >> 2);
    const int c8 = (threadIdx.x & 3) * 8;
    if (n >= N) return;

    const float di = dinv[n];
    half8v hs = *(const half8v*)&hq[(long long)n * 32 + c8];
    float acc[8];
    const float sd = di * di;
#pragma unroll
    for (int j = 0; j < 8; ++j) acc[j] = (float)hs[j] * sd;

    int j = offs[n];
    const int end = offs[n + 1];
    for (; j + 7 < end; j += 8) {
        int s[8];
        float ws[8];
        half8v v[8];
#pragma unroll
        for (int u = 0; u < 8; ++u) s[u] = csr[j + u];
#pragma unroll
        for (int u = 0; u < 8; ++u) ws[u] = dinv[s[u]];
#pragma unroll
        for (int u = 0; u < 8; ++u) v[u] = *(const half8v*)&hq[(long long)s[u] * 32 + c8];
#pragma unroll
        for (int u = 0; u < 8; ++u) {
            float w = ws[u] * di;
#pragma unroll
            for (int t = 0; t < 8; ++t) acc[t] = fmaf((float)v[u][t], w, acc[t]);
        }
    }
    for (; j < end; ++j) {
        int s = csr[j];
        float w = dinv[s] * di;
        half8v v = *(const half8v*)&hq[(long long)s * 32 + c8];
#pragma unroll
        for (int t = 0; t < 8; ++t) acc[t] = fmaf((float)v[t], w, acc[t]);
    }

    float4 b0 = *(const float4*)&bias[c8];
    float4 b1 = *(const float4*)&bias[c8 + 4];
    float bb[8] = {b0.x, b0.y, b0.z, b0.w, b1.x, b1.y, b1.z, b1.w};
#pragma unroll
    for (int t = 0; t < 8; ++t) {
        acc[t] += bb[t];
        if (RELU) acc[t] = fmaxf(acc[t], 0.f);
    }
    float* o = &outp[(long long)n * ostride + c8];
    *(float4*)o       = make_float4(acc[0], acc[1], acc[2], acc[3]);
    *(float4*)(o + 4) = make_float4(acc[4], acc[5], acc[6], acc[7]);
}

extern "C" void kernel_launch(void* const* d_in, const int* in_sizes, int n_in,
                              void* d_out, int out_size, void* d_ws, size_t ws_size,
                              hipStream_t stream) {
    const float* x  = (const float*)d_in[0];
    const int*   ei = (const int*)d_in[1];
    const float* W1 = (const float*)d_in[2];
    const float* b1 = (const float*)d_in[3];
    const float* W2 = (const float*)d_in[4];
    const float* b2 = (const float*)d_in[5];
    float* out = (float*)d_out;

    const int IN_CH = 256, HID = 128, OUT = 64;
    const int N = in_sizes[0] / IN_CH;     // 50000
    const int E = in_sizes[1] / 2;         // 800000
    const int NB = (N + BUCK - 1) / BUCK;  // 782 buckets (< 1024)
    const int chunk = (E + NBLK - 1) / NBLK;

    char* w = (char*)d_ws;
    size_t off_b = 0;
    auto alloc = [&](size_t bytes) { void* p = w + off_b; off_b = (off_b + bytes + 255) & ~(size_t)255; return p; };
    int*   flag    = (int*)alloc(256);
    int*   hist2   = (int*)alloc((size_t)NBLK * NB * 4);
    int*   start2t = (int*)alloc((size_t)NB * NBLK * 4);
    int*   colsum  = (int*)alloc((size_t)NB * 4);
    int*   bbase   = (int*)alloc((size_t)(NB + 1) * 4);
    int*   offs    = (int*)alloc((size_t)(N + 1) * 4);
    float* dinv    = (float*)alloc((size_t)N * 4);
    unsigned* ebuf = (unsigned*)alloc((size_t)E * 4);
    int*   csr     = (int*)alloc((size_t)E * 4);
    _Float16* W1t  = (_Float16*)alloc((size_t)IN_CH * HID * 2);
    _Float16* W2t  = (_Float16*)alloc((size_t)HID * OUT * 2);
    _Float16* h1   = (_Float16*)alloc((size_t)N * HID * 2); // 4 planes [N][32]; reused as h2
    float* agg1    = (float*)alloc((size_t)N * HID * 4);    // fp32 row-major
    _Float16* h2   = h1;                                    // 2 planes [N][32]

    const int T = 256;
    detect64_kernel<<<1, 256, 0, stream>>>(ei, flag);
    hist2_kernel<<<NBLK, T, 0, stream>>>(ei, flag, hist2, E, NB, chunk);
    colscan_kernel<<<(NB + T - 1) / T, T, 0, stream>>>(hist2, start2t, colsum, NB);
    basescan_kernel<<<1, 1024, 0, stream>>>(colsum, bbase, NB, E);
    scatter2_kernel<<<NBLK, T, 0, stream>>>(ei, flag, bbase, start2t, ebuf, E, NB, chunk);
    csrbuild_kernel<<<NB, T, 0, stream>>>(ebuf, bbase, offs, dinv, csr, N, NB, E);

    {
        int nb1 = (IN_CH * HID + T - 1) / T;
        int nb2 = (HID * OUT + T - 1) / T;
        convW_kernel<<<nb1 + nb2, T, 0, stream>>>(W1, W1t, IN_CH, HID, nb1,
                                                  W2, W2t, HID, OUT);
    }

    const int gblocks = (N + 63) / 64;

    // GEMM1: h1 planes[4][N][32](fp16) = x[N,256] @ W1
    gemm_f16_kernel<128, 256><<<(N + 127) / 128, 256, 0, stream>>>(x, W1t, h1, N);
    // layer-1 aggregation: one dispatch per 3.2MB plane (L2-resident gather)
    for (int q = 0; q < 4; ++q) {
        gatherq_kernel<1><<<gblocks, 256, 0, stream>>>(
            h1 + (size_t)q * N * 32, csr, offs, dinv, b1 + q * 32,
            agg1 + q * 32, HID, N);
    }
    // GEMM2: h2 planes[2][N][32](fp16) = agg1[N,128] @ W2
    gemm_f16_kernel<64, 128><<<(N + 127) / 128, 256, 0, stream>>>(agg1, W2t, h2, N);
    // layer-2 aggregation: 2 plane dispatches -> out (fp32 row-major)
    for (int q = 0; q < 2; ++q) {
        gatherq_kernel<0><<<gblocks, 256, 0, stream>>>(
            h2 + (size_t)q * N * 32, csr, offs, dinv, b2 + q * 32,
            out + q * 32, OUT, N);
    }
}

// Round 10
// 240.570 us; speedup vs baseline: 1.1501x; 1.1501x over previous
//
#include <hip/hip_runtime.h>

// ---------------------------------------------------------------------------
// GCN encoder: out = GCNConv2( relu(GCNConv1(x)) )
// R9: revert R8 plane-split (XCD L2 replication makes it a net loss).
// Single row-major fp16 gathers with clamped 8-edge rounds (no serial tail).
// Parallel colscan/basescan CSR build kept. GEMM = R7 async-LDS fp16 MFMA.
// ---------------------------------------------------------------------------

typedef __attribute__((ext_vector_type(4))) float floatx4;
typedef _Float16 __attribute__((ext_vector_type(8))) half8v;

#define BUCK_SH 6
#define BUCK    64           // dsts per bucket
#define NBLK    256          // blocks for hist2/scatter2

#define AS1(p) ((const __attribute__((address_space(1))) void*)(p))
#define AS3(p) ((__attribute__((address_space(3))) void*)(p))

// edge_index may arrive as int64 (reference dtype) or int32 (harness contract).
__global__ void detect64_kernel(const int* __restrict__ ei, int* __restrict__ flag) {
    __shared__ int nz;
    if (threadIdx.x == 0) nz = 0;
    __syncthreads();
    if (ei[2 * threadIdx.x + 1] != 0) atomicOr(&nz, 1);
    __syncthreads();
    if (threadIdx.x == 0) *flag = (nz == 0) ? 1 : 0;
}

__device__ __forceinline__ int edge_id(const int* __restrict__ ei, int is64, long long pos) {
    return is64 ? ei[2 * pos] : ei[(int)pos];
}

// ---- per-block bucket histogram -> hist2[blk][NB] (no global atomics) ------
__global__ void hist2_kernel(const int* __restrict__ ei, const int* __restrict__ flag,
                             int* __restrict__ hist2, int E, int NB, int chunk) {
    __shared__ int h[1024];
    const int t = threadIdx.x;
    for (int i = t; i < NB; i += blockDim.x) h[i] = 0;
    __syncthreads();
    const int is64 = *flag;
    const int lo = blockIdx.x * chunk;
    const int hi = min(E, lo + chunk);
    for (int e = lo + t; e < hi; e += blockDim.x) {
        int d = edge_id(ei, is64, (long long)E + e);
        atomicAdd(&h[d >> BUCK_SH], 1);
    }
    __syncthreads();
    for (int i = t; i < NB; i += blockDim.x) hist2[(long long)blockIdx.x * NB + i] = h[i];
}

// ---- per-bucket column scan: start2t[bucket][blk] + colsum[bucket] ---------
__global__ void colscan_kernel(const int* __restrict__ hist2, int* __restrict__ start2t,
                               int* __restrict__ colsum, int NB) {
    int t = blockIdx.x * blockDim.x + threadIdx.x;    // bucket id
    if (t >= NB) return;
    int run = 0;
    for (int b = 0; b < NBLK; ++b) {
        int v = hist2[(long long)b * NB + t];         // coalesced across wave
        start2t[(long long)t * NBLK + b] = run;       // contiguous per thread
        run += v;
    }
    colsum[t] = run;
}

// ---- tiny single-block exclusive scan of colsum -> bbase[NB+1] -------------
__global__ void basescan_kernel(const int* __restrict__ colsum, int* __restrict__ bbase,
                                int NB, int E) {
    __shared__ int sm[1024];
    const int t = threadIdx.x;
    int v = (t < NB) ? colsum[t] : 0;
    sm[t] = v;
    __syncthreads();
    for (int s = 1; s < 1024; s <<= 1) {
        int u = (t >= s) ? sm[t - s] : 0;
        __syncthreads();
        sm[t] += u;
        __syncthreads();
    }
    if (t < NB) bbase[t] = sm[t] - v;
    if (t == 0) bbase[NB] = E;
}

// ---- scatter: LDS cursors only, packed record src | (dlocal<<26) -----------
__global__ void scatter2_kernel(const int* __restrict__ ei, const int* __restrict__ flag,
                                const int* __restrict__ bbase, const int* __restrict__ start2t,
                                unsigned* __restrict__ ebuf, int E, int NB, int chunk) {
    __shared__ int hcur[1024];
    const int t = threadIdx.x;
    for (int i = t; i < NB; i += blockDim.x)
        hcur[i] = bbase[i] + start2t[(long long)i * NBLK + blockIdx.x];
    __syncthreads();
    const int is64 = *flag;
    const int lo = blockIdx.x * chunk;
    const int hi = min(E, lo + chunk);
    for (int e = lo + t; e < hi; e += blockDim.x) {
        int s = edge_id(ei, is64, e);
        int d = edge_id(ei, is64, (long long)E + e);
        int pos = atomicAdd(&hcur[d >> BUCK_SH], 1);
        ebuf[pos] = (unsigned)s | ((unsigned)(d & (BUCK - 1)) << 26);
    }
}

// ---- per-bucket exact CSR build: offs, dinv, csr(src only) -----------------
__global__ void csrbuild_kernel(const unsigned* __restrict__ ebuf, const int* __restrict__ bbase,
                                int* __restrict__ offs, float* __restrict__ dinv,
                                int* __restrict__ csr, int N, int NB, int E) {
    __shared__ int cnt[BUCK], exc[BUCK], cur[BUCK];
    const int b = blockIdx.x;
    const int t = threadIdx.x;
    if (t < BUCK) { cnt[t] = 0; cur[t] = 0; }
    __syncthreads();
    const int lo = bbase[b], hi = bbase[b + 1];
    for (int i = lo + t; i < hi; i += blockDim.x)
        atomicAdd(&cnt[ebuf[i] >> 26], 1);
    __syncthreads();
    if (t == 0) {
        int run = 0;
        for (int l = 0; l < BUCK; ++l) { exc[l] = run; run += cnt[l]; }
    }
    __syncthreads();
    if (t < BUCK) {
        int n = b * BUCK + t;
        if (n < N) {
            offs[n] = lo + exc[t];
            dinv[n] = rsqrtf(1.0f + (float)cnt[t]);
        }
    }
    if (b == NB - 1 && t == 0) offs[N] = E;
    for (int i = lo + t; i < hi; i += blockDim.x) {
        unsigned e = ebuf[i];
        int l = e >> 26;
        int p = lo + exc[l] + atomicAdd(&cur[l], 1);
        csr[p] = (int)(e & 0x03FFFFFFu);
    }
}

// ---------------------------------------------------------------------------
// Weight pre-transform: W[K][Nc] fp32 -> Wt [Nc][K] fp16
// ---------------------------------------------------------------------------
__device__ __forceinline__ void convW_one(const float* W, _Float16* Wt, int K, int Nc, int idx) {
    if (idx >= K * Nc) return;
    int k = idx / Nc, n = idx % Nc;
    Wt[(long long)n * K + k] = (_Float16)W[idx];
}

__global__ void convW_kernel(const float* __restrict__ W1, _Float16* __restrict__ T1,
                             int K1, int N1, int nb1,
                             const float* __restrict__ W2, _Float16* __restrict__ T2,
                             int K2, int N2) {
    if ((int)blockIdx.x < nb1) {
        convW_one(W1, T1, K1, N1, blockIdx.x * blockDim.x + threadIdx.x);
    } else {
        convW_one(W2, T2, K2, N2, (blockIdx.x - nb1) * blockDim.x + threadIdx.x);
    }
}

// ---------------------------------------------------------------------------
// fp16 MFMA GEMM: C[M,NCOL](fp16) = A[M,K](fp32) @ B[K,NCOL]
// B pre-transposed fp16 [NCOL][K] (L2-resident). BM=128, BK=64, 4 waves,
// RT=2 row-tiles/wave. A staged fp32 via async global_load_lds (width 16),
// double-buffered, XOR-swizzled 16B units for conflict-free ds_read_b128.
// ---------------------------------------------------------------------------
template <int NCOL, int K>
__launch_bounds__(256)
__global__ void gemm_f16_kernel(const float* __restrict__ A,
                                const _Float16* __restrict__ Bt,
                                _Float16* __restrict__ C, int M) {
    constexpr int NCB = NCOL / 16;
    constexpr int BM = 128, BK = 64;
    constexpr int NC = K / BK;                 // 4 (GEMM1) / 2 (GEMM2)
    constexpr int UNITS = BM * BK / 4;         // 16B units per chunk = 2048
    __shared__ float As[2][BM * BK];           // 2 x 32 KB

    const int tid  = threadIdx.x;
    const int wave = tid >> 6;
    const int lane = tid & 63;
    const int n15  = lane & 15;
    const int q    = lane >> 4;
    const int row0 = blockIdx.x * BM;

    floatx4 acc[2][NCB];
#pragma unroll
    for (int rt = 0; rt < 2; ++rt)
#pragma unroll
        for (int c = 0; c < NCB; ++c) acc[rt][c] = (floatx4){0.f, 0.f, 0.f, 0.f};

    auto stage = [&](int buf, int kc) {
#pragma unroll
        for (int j = 0; j < UNITS / 256; ++j) {
            int g = j * 256 + tid;
            int r = g >> 4;
            int u = (g & 15) ^ (r & 15);
            int gr = row0 + r;
            if (gr >= M) gr = M - 1;
            const float* gp = &A[(long long)gr * K + kc + u * 4];
            float* lp = &As[buf][g * 4];
            __builtin_amdgcn_global_load_lds(AS1(gp), AS3(lp), 16, 0, 0);
        }
    };

    stage(0, 0);
    __syncthreads();

#pragma unroll
    for (int c = 0; c < NC; ++c) {
        if (c + 1 < NC) stage((c + 1) & 1, (c + 1) * BK);   // async prefetch
        const int buf = c & 1;
#pragma unroll
        for (int ks = 0; ks < 2; ++ks) {                    // two K=32 sub-steps
            half8v af[2];
#pragma unroll
            for (int rt = 0; rt < 2; ++rt) {
                const int R = wave * 32 + rt * 16 + n15;
                const int u0 = ks * 8 + q * 2;
                const int p0 = (u0)     ^ (R & 15);
                const int p1 = (u0 + 1) ^ (R & 15);
                float4 f0 = *(const float4*)&As[buf][R * BK + p0 * 4];
                float4 f1 = *(const float4*)&As[buf][R * BK + p1 * 4];
                af[rt][0] = (_Float16)f0.x; af[rt][1] = (_Float16)f0.y;
                af[rt][2] = (_Float16)f0.z; af[rt][3] = (_Float16)f0.w;
                af[rt][4] = (_Float16)f1.x; af[rt][5] = (_Float16)f1.y;
                af[rt][6] = (_Float16)f1.z; af[rt][7] = (_Float16)f1.w;
            }
#pragma unroll
            for (int cb = 0; cb < NCB; ++cb) {
                const _Float16* bp = &Bt[(long long)(cb * 16 + n15) * K + c * BK + ks * 32 + q * 8];
                half8v bf = *(const half8v*)bp;
                acc[0][cb] = __builtin_amdgcn_mfma_f32_16x16x32_f16(af[0], bf, acc[0][cb], 0, 0, 0);
                acc[1][cb] = __builtin_amdgcn_mfma_f32_16x16x32_f16(af[1], bf, acc[1][cb], 0, 0, 0);
            }
        }
        if (c + 1 < NC) __syncthreads();
    }

    // C/D layout: col = cb*16 + n15, row-in-tile = q*4 + reg
#pragma unroll
    for (int rt = 0; rt < 2; ++rt) {
#pragma unroll
        for (int cb = 0; cb < NCB; ++cb) {
            int col = cb * 16 + n15;
#pragma unroll
            for (int r = 0; r < 4; ++r) {
                int gr = row0 + wave * 32 + rt * 16 + q * 4 + r;
                if (gr < M) C[(long long)gr * NCOL + col] = (_Float16)acc[rt][cb][r];
            }
        }
    }
}

// ---------------------------------------------------------------------------
// Gather aggregation, fp16 h, 8 channels/lane. Clamped 8-edge rounds:
// every edge load issues inside an 8-deep MLP batch (no serial tail loop);
// out-of-range slots clamp the index and zero the weight.
// out[n][:] = (h[n]*dinv[n]^2 + sum_e h[src]*dinv[src]*dinv[n]) + bias (,relu)
// ---------------------------------------------------------------------------
template <int F, int RELU>
__launch_bounds__(256)
__global__ void gatherh_kernel(const _Float16* __restrict__ h, const int* __restrict__ csr,
                               const int* __restrict__ offs, const float* __restrict__ dinv,
                               const float* __restrict__ bias, float* __restrict__ out, int N) {
    constexpr int L = F / 8;            // lanes per node
    constexpr int NPB = 256 / L;        // nodes per block
    const int n = blockIdx.x * NPB + threadIdx.x / L;
    const int c8 = (threadIdx.x % L) * 8;
    if (n >= N) return;

    const float di = dinv[n];
    half8v hs = *(const half8v*)&h[(long long)n * F + c8];
    float acc[8];
    const float sd = di * di;
#pragma unroll
    for (int j = 0; j < 8; ++j) acc[j] = (float)hs[j] * sd;

    const int end = offs[n + 1];
    for (int j = offs[n]; j < end; j += 8) {
        int s[8];
        float ws[8];
        half8v v[8];
#pragma unroll
        for (int u = 0; u < 8; ++u) {
            int jj = j + u;
            s[u] = csr[jj < end ? jj : end - 1];
        }
#pragma unroll
        for (int u = 0; u < 8; ++u)
            ws[u] = (j + u < end) ? dinv[s[u]] * di : 0.f;
#pragma unroll
        for (int u = 0; u < 8; ++u) v[u] = *(const half8v*)&h[(long long)s[u] * F + c8];
#pragma unroll
        for (int u = 0; u < 8; ++u) {
#pragma unroll
            for (int t = 0; t < 8; ++t) acc[t] = fmaf((float)v[u][t], ws[u], acc[t]);
        }
    }

    float4 b0 = *(const float4*)&bias[c8];
    float4 b1 = *(const float4*)&bias[c8 + 4];
    float bb[8] = {b0.x, b0.y, b0.z, b0.w, b1.x, b1.y, b1.z, b1.w};
#pragma unroll
    for (int t = 0; t < 8; ++t) {
        acc[t] += bb[t];
        if (RELU) acc[t] = fmaxf(acc[t], 0.f);
    }
    float* o = &out[(long long)n * F + c8];
    *(float4*)o       = make_float4(acc[0], acc[1], acc[2], acc[3]);
    *(float4*)(o + 4) = make_float4(acc[4], acc[5], acc[6], acc[7]);
}

extern "C" void kernel_launch(void* const* d_in, const int* in_sizes, int n_in,
                              void* d_out, int out_size, void* d_ws, size_t ws_size,
                              hipStream_t stream) {
    const float* x  = (const float*)d_in[0];
    const int*   ei = (const int*)d_in[1];
    const float* W1 = (const float*)d_in[2];
    const float* b1 = (const float*)d_in[3];
    const float* W2 = (const float*)d_in[4];
    const float* b2 = (const float*)d_in[5];
    float* out = (float*)d_out;

    const int IN_CH = 256, HID = 128, OUT = 64;
    const int N = in_sizes[0] / IN_CH;     // 50000
    const int E = in_sizes[1] / 2;         // 800000
    const int NB = (N + BUCK - 1) / BUCK;  // 782 buckets (< 1024)
    const int chunk = (E + NBLK - 1) / NBLK;

    char* w = (char*)d_ws;
    size_t off_b = 0;
    auto alloc = [&](size_t bytes) { void* p = w + off_b; off_b = (off_b + bytes + 255) & ~(size_t)255; return p; };
    int*   flag    = (int*)alloc(256);
    int*   hist2   = (int*)alloc((size_t)NBLK * NB * 4);
    int*   start2t = (int*)alloc((size_t)NB * NBLK * 4);
    int*   colsum  = (int*)alloc((size_t)NB * 4);
    int*   bbase   = (int*)alloc((size_t)(NB + 1) * 4);
    int*   offs    = (int*)alloc((size_t)(N + 1) * 4);
    float* dinv    = (float*)alloc((size_t)N * 4);
    unsigned* ebuf = (unsigned*)alloc((size_t)E * 4);
    int*   csr     = (int*)alloc((size_t)E * 4);
    _Float16* W1t  = (_Float16*)alloc((size_t)IN_CH * HID * 2);
    _Float16* W2t  = (_Float16*)alloc((size_t)HID * OUT * 2);
    _Float16* h1   = (_Float16*)alloc((size_t)N * HID * 2); // fp16; reused as h2
    float* agg1    = (float*)alloc((size_t)N * HID * 4);    // fp32
    _Float16* h2   = h1;

    const int T = 256;
    detect64_kernel<<<1, 256, 0, stream>>>(ei, flag);
    hist2_kernel<<<NBLK, T, 0, stream>>>(ei, flag, hist2, E, NB, chunk);
    colscan_kernel<<<(NB + T - 1) / T, T, 0, stream>>>(hist2, start2t, colsum, NB);
    basescan_kernel<<<1, 1024, 0, stream>>>(colsum, bbase, NB, E);
    scatter2_kernel<<<NBLK, T, 0, stream>>>(ei, flag, bbase, start2t, ebuf, E, NB, chunk);
    csrbuild_kernel<<<NB, T, 0, stream>>>(ebuf, bbase, offs, dinv, csr, N, NB, E);

    {
        int nb1 = (IN_CH * HID + T - 1) / T;
        int nb2 = (HID * OUT + T - 1) / T;
        convW_kernel<<<nb1 + nb2, T, 0, stream>>>(W1, W1t, IN_CH, HID, nb1,
                                                  W2, W2t, HID, OUT);
    }

    // GEMM1: h1[N,128](fp16) = x[N,256] @ W1
    gemm_f16_kernel<128, 256><<<(N + 127) / 128, 256, 0, stream>>>(x, W1t, h1, N);
    // layer-1 aggregation (fp16 gather, fused self-loop + bias + relu) -> agg1 (fp32)
    gatherh_kernel<128, 1><<<(N * 16 + 255) / 256, 256, 0, stream>>>(h1, csr, offs, dinv, b1, agg1, N);
    // GEMM2: h2[N,64](fp16) = agg1[N,128] @ W2
    gemm_f16_kernel<64, 128><<<(N + 127) / 128, 256, 0, stream>>>(agg1, W2t, h2, N);
    // layer-2 aggregation (fp16 gather, fused self-loop + bias) -> out (fp32)
    gatherh_kernel<64, 0><<<(N * 8 + 255) / 256, 256, 0, stream>>>(h2, csr, offs, dinv, b2, out, N);
}